// Round 7
// baseline (560.453 us; speedup 1.0000x reference)
//
#include <hip/hip_runtime.h>
#include <math.h>

#define B_ 8
#define L_ 2048
#define DM 6
#define ED 48
#define NS 32
#define DCONV 16
#define NLAYERS 4
#define NCLASSES 4
#define EPS 1e-5f

#define NBLK 512           // 2 blocks/CU co-resident (persistent)
#define EDL (B_ * ED * L_)     // 786432 floats
#define NSL (B_ * L_ * NS)     // 524288
#define DML (B_ * DM * L_)     // 98304

// Per-layer buffer instances (WRITE-ONCE per execution -> no stale-L1 hazard
// without any cache maintenance; see barrier design below).
// layout per layer: z, xc, delta, y, Bm, Cm, h
#define LSTRIDE (4 * EDL + 2 * NSL + DML)   // 4,292,608 floats/layer
#define WS_BAR (NLAYERS * LSTRIDE)          // float offset of barrier area

// barrier area (u32): reg[8][16] | gcnt[16] | bar[9 groups][8 epochs][16]
#define BAR_U32 (8 * 16 + 16 + 9 * 8 * 16)
#define BAR_BYTES (BAR_U32 * 4)

// ---------------------------------------------------------------------------
// Round-7: RESUBMISSION of the round-6 kernel. Round 6 never executed
// ("container failed twice" = infra failure before any pytest/compile
// output). No code changes vs round 6; see its header below.
//
// Round-6 changes (on top of round-5's fence-free XCD-local design):
//  * Bm/Cm layout [b][l][n] -> [b][n][l]: scan lane n streams its own row
//    as float4 (4x fewer load issues vs scalar strided); PRE phase-5 stores
//    become 8 li-coalesced scalar stores.
//  * Scan: 16 spans of 128 steps; each 32-lane group owns TWO interleaved
//    spans (2 independent h-recurrences per lane -> 2x ILP / loads in
//    flight). Rationale: round-5 counters (VALUBusy 24%, HBM 2.8%, occupancy
//    22.6% == grid-limited 8 waves/CU) say we are latency/issue-bound; grid
//    can't grow without PRE restructure, so raise per-wave ILP instead.
//    VGPR headroom is free: grid limits us to 2 waves/SIMD which allows 256.
// ---------------------------------------------------------------------------

__global__ void __launch_bounds__(256, 2) k_all(
    const float* __restrict__ x,
    const float* __restrict__ in_proj_w,
    const float* __restrict__ conv_w,
    const float* __restrict__ conv_b,
    const float* __restrict__ x_proj_w,
    const float* __restrict__ dt_proj_w,
    const float* __restrict__ dt_proj_b,
    const float* __restrict__ A_log,
    const float* __restrict__ Dp,
    const float* __restrict__ out_proj_w,
    const float* __restrict__ norm_w,
    const float* __restrict__ fc_w,
    const float* __restrict__ fc_b,
    float* __restrict__ out,
    float* __restrict__ ws)
{
    unsigned* ureg = (unsigned*)(ws + WS_BAR);   // [8][16] per-XCD block counts
    unsigned* gcnt = ureg + 8 * 16;              // [16] global registration
    unsigned* bar  = gcnt + 16;                  // [9][8][16] group x epoch

    __shared__ float sh[DM][48];     // residual h, 47 positions (l0-15..l0+31)
    __shared__ float sxin[ED][48];   // xin (47 pos); also reused as y-staging
    __shared__ float sxc[ED][33];    // xc, 32 positions (+1 pad)
    __shared__ float srn[48];        // rms scale per position
    __shared__ float sdr[32];        // dt-rank scalar per position
    __shared__ float sA[16][32];     // scan span summaries: exp(A*sum d)
    __shared__ float sH[16][32];     // scan span summaries: local end h
    __shared__ int s_xcd, s_lidx, s_n, s_mode;

    const int tid = threadIdx.x;

    // ---------------- registration: discover block->XCD mapping ------------
    if (tid == 0) {
        unsigned xcd;
        asm volatile("s_getreg_b32 %0, hwreg(HW_REG_XCC_ID)" : "=s"(xcd));
        xcd &= 7u;
        int lidx = (int)__hip_atomic_fetch_add(&ureg[xcd * 16], 1u,
                        __ATOMIC_RELAXED, __HIP_MEMORY_SCOPE_AGENT);
        __hip_atomic_fetch_add(&gcnt[0], 1u,
                        __ATOMIC_RELAXED, __HIP_MEMORY_SCOPE_AGENT);
        while (__hip_atomic_load(&gcnt[0], __ATOMIC_RELAXED,
                                 __HIP_MEMORY_SCOPE_AGENT) < (unsigned)NBLK)
            __builtin_amdgcn_s_sleep(1);
        int npres = 0;
        for (int xx = 0; xx < 8; ++xx) {
            unsigned c = __hip_atomic_load(&ureg[xx * 16], __ATOMIC_RELAXED,
                                           __HIP_MEMORY_SCOPE_AGENT);
            if (c) npres++;
        }
        unsigned nm = __hip_atomic_load(&ureg[xcd * 16], __ATOMIC_RELAXED,
                                        __HIP_MEMORY_SCOPE_AGENT);
        s_xcd = (int)xcd; s_lidx = lidx; s_n = (int)nm;
        s_mode = (npres == 8) ? 0 : 1;
    }
    __syncthreads();

    const int  mode  = s_mode;                       // 0 = XCD-local, 1 = fallback
    const int  grp   = mode ? 8 : s_xcd;             // barrier group id
    const unsigned gsz = mode ? (unsigned)NBLK : (unsigned)s_n;
    const int  lidx  = mode ? (int)blockIdx.x : s_lidx;
    const int  nwork = mode ? NBLK : s_n;
    const int  b0    = mode ? 0 : s_xcd;             // batches this group owns
    const int  bN    = mode ? B_ : s_xcd + 1;

    // group barrier: counters only (normal mode); full fences in fallback
    auto gbar = [&](int epoch) {
        __syncthreads();
        if (tid == 0) {
            unsigned* c = &bar[(grp * 8 + epoch) * 16];
            if (mode) __threadfence();
            asm volatile("" ::: "memory");
            __hip_atomic_fetch_add(c, 1u, __ATOMIC_RELAXED,
                                   __HIP_MEMORY_SCOPE_AGENT);
            while (__hip_atomic_load(c, __ATOMIC_RELAXED,
                                     __HIP_MEMORY_SCOPE_AGENT) < gsz)
                __builtin_amdgcn_s_sleep(2);
            asm volatile("" ::: "memory");
            if (mode) __threadfence();
        }
        __syncthreads();
    };

    for (int layer = 0; layer < NLAYERS; ++layer) {
        const float* ipw = in_proj_w + (size_t)layer * 96 * DM;
        const float* nw  = norm_w    + (size_t)layer * DM;
        const float* cw  = conv_w    + (size_t)layer * ED * DCONV;
        const float* cb  = conv_b    + (size_t)layer * ED;
        const float* xpw = x_proj_w  + (size_t)layer * 65 * ED;
        const float* dtw = dt_proj_w + (size_t)layer * ED;
        const float* dtb = dt_proj_b + (size_t)layer * ED;
        const float* al  = A_log     + (size_t)layer * ED * NS;
        const float* dpp = Dp        + (size_t)layer * ED;
        const float* ow  = (layer == 0) ? out_proj_w
                          : out_proj_w + (size_t)(layer - 1) * DM * ED;

        float* Lb    = ws + (size_t)layer * LSTRIDE;
        float* zL    = Lb;
        float* xcL   = zL  + EDL;
        float* dL    = xcL + EDL;
        float* yL    = dL  + EDL;
        float* BmL   = yL  + EDL;                    // [b][n][l]
        float* CmL   = BmL + NSL;                    // [b][n][l]
        float* hL    = CmL + NSL;                    // h written by this layer
        const float* hprev = (layer > 0) ? (ws + (size_t)(layer-1) * LSTRIDE
                                            + 4 * EDL + 2 * NSL) : nullptr;
        const float* yprev = (layer > 0) ? (ws + (size_t)(layer-1) * LSTRIDE
                                            + 3 * EDL) : nullptr;

        // ================= PRE: 64 tiles per batch =========================
        for (int bb = b0; bb < bN; ++bb) {
            for (int t = lidx; t < 64; t += nwork) {
                const int b  = bb;
                const int l0 = t * 32;

                // Phase 1: residual h for 47 positions
                if (layer > 0) {
                    for (int i = tid; i < ED * 47; i += 256) {
                        int e = i / 47, p = i % 47;
                        int l = l0 - 15 + p;
                        sxin[e][p] = (l >= 0)
                            ? yprev[((size_t)b * ED + e) * L_ + l] : 0.f;
                    }
                    __syncthreads();
                    for (int i = tid; i < DM * 47; i += 256) {
                        int d = i / 47, p = i % 47;
                        int l = l0 - 15 + p;
                        float hv = 0.f;
                        if (l >= 0) {
                            hv = hprev[((size_t)b * DM + d) * L_ + l];
                            const float* wp = ow + d * ED;
                            float acc = 0.f;
#pragma unroll
                            for (int e = 0; e < ED; ++e) acc += sxin[e][p] * wp[e];
                            hv += acc;
                            if (p >= 15 && layer < NLAYERS - 1)
                                hL[((size_t)b * DM + d) * L_ + l] = hv;
                        }
                        sh[d][p] = hv;
                    }
                } else {
                    for (int i = tid; i < DM * 47; i += 256) {
                        int d = i / 47, p = i % 47;
                        int l = l0 - 15 + p;
                        float hv = 0.f;
                        if (l >= 0) {
                            hv = x[((size_t)b * L_ + l) * DM + d];
                            if (p >= 15)
                                hL[((size_t)b * DM + d) * L_ + l] = hv;
                        }
                        sh[d][p] = hv;
                    }
                }
                __syncthreads();

                // Phase 2: rms scale per position
                if (tid < 47) {
                    float ss = 0.f;
#pragma unroll
                    for (int d = 0; d < DM; ++d) ss += sh[d][tid] * sh[d][tid];
                    srn[tid] = rsqrtf(ss * (1.f / DM) + EPS);
                }
                __syncthreads();

                // Phase 3a: xin (47 positions, into LDS)
                for (int i = tid; i < ED * 47; i += 256) {
                    int e = i / 47, p = i % 47;
                    const float* wp = ipw + e * DM;
                    float acc = 0.f;
#pragma unroll
                    for (int d = 0; d < DM; ++d) acc += sh[d][p] * nw[d] * wp[d];
                    sxin[e][p] = acc * srn[p];
                }
                // Phase 3b: z (32 owned positions, to global)
                for (int i = tid; i < ED * 32; i += 256) {
                    int e = i >> 5, po = i & 31;
                    int p = po + 15;
                    const float* wp = ipw + (ED + e) * DM;
                    float acc = 0.f;
#pragma unroll
                    for (int d = 0; d < DM; ++d) acc += sh[d][p] * nw[d] * wp[d];
                    zL[((size_t)b * ED + e) * L_ + l0 + po] = acc * srn[p];
                }
                __syncthreads();

                // Phase 4: conv + SiLU
                for (int i = tid; i < ED * 32; i += 256) {
                    int e = i >> 5, po = i & 31;
                    const float* wp = cw + e * DCONV;
                    float acc = cb[e];
#pragma unroll
                    for (int k = 0; k < DCONV; ++k) acc += sxin[e][po + k] * wp[k];
                    float v = acc / (1.f + __expf(-acc));
                    sxc[e][po] = v;
                    xcL[((size_t)b * ED + e) * L_ + l0 + po] = v;
                }
                __syncthreads();

                // Phase 5: x_proj -> Bm/Cm in [b][n][l] layout
                {
                    int og = tid >> 5, li = tid & 31;
                    int isB = og < 4;
                    int nb = isB ? og * 8 : (og - 4) * 8;
                    int rowBase = isB ? (1 + nb) : (1 + NS + nb);
                    const float* wr = xpw + rowBase * ED;
                    float a0=0,a1=0,a2=0,a3=0,a4=0,a5=0,a6=0,a7=0, dr=0;
#pragma unroll 4
                    for (int e = 0; e < ED; ++e) {
                        float xv = sxc[e][li];
                        a0 += xv * wr[0*ED+e]; a1 += xv * wr[1*ED+e];
                        a2 += xv * wr[2*ED+e]; a3 += xv * wr[3*ED+e];
                        a4 += xv * wr[4*ED+e]; a5 += xv * wr[5*ED+e];
                        a6 += xv * wr[6*ED+e]; a7 += xv * wr[7*ED+e];
                        dr += xv * xpw[e];
                    }
                    float* dst = (isB ? BmL : CmL)
                               + ((size_t)b * NS + nb) * L_ + l0 + li;
                    dst[0 * L_] = a0; dst[1 * L_] = a1;
                    dst[2 * L_] = a2; dst[3 * L_] = a3;
                    dst[4 * L_] = a4; dst[5 * L_] = a5;
                    dst[6 * L_] = a6; dst[7 * L_] = a7;
                    if (og == 0) sdr[li] = dr;
                }
                __syncthreads();

                // Phase 6: delta = softplus(dr*dtw + dtb)
                for (int i = tid; i < ED * 32; i += 256) {
                    int e = i >> 5, po = i & 31;
                    float s = sdr[po] * dtw[e] + dtb[e];
                    dL[((size_t)b * ED + e) * L_ + l0 + po] =
                        fmaxf(s, 0.f) + log1pf(__expf(-fabsf(s)));
                }
                __syncthreads();   // LDS quiescent before next tile
            }
        }
        gbar(layer * 2 + 0);

        // ================= SCAN: one chain (b,e) per block ==================
        // 16 spans of 128 steps; group gid owns spans {2gid, 2gid+1} as two
        // interleaved register streams (2x ILP on the dependent fma chain).
        for (int bb = b0; bb < bN; ++bb) {
            for (int ch = lidx; ch < ED; ch += nwork) {
                const int e   = ch;
                const int b   = bb;
                const int gid = tid >> 5;
                const int n   = tid & 31;
                const float A  = -__expf(al[e * NS + n]);
                const float Dv = dpp[e];

                const size_t eRow = (size_t)(b * ED + e) * L_;
                const size_t nRow = ((size_t)b * NS + n) * L_;
                const int la = (2 * gid) * 128;        // span A start
                const int lb = la + 128;               // span B start
                const float4* dRa = (const float4*)(dL  + eRow + la);
                const float4* xRa = (const float4*)(xcL + eRow + la);
                const float4* bRa = (const float4*)(BmL + nRow + la);
                const float4* cRa = (const float4*)(CmL + nRow + la);
                const float*  zRa = zL + eRow + la;
                float*        yRa = yL + eRow + la;
                const float4* dRb = (const float4*)(dL  + eRow + lb);
                const float4* xRb = (const float4*)(xcL + eRow + lb);
                const float4* bRb = (const float4*)(BmL + nRow + lb);
                const float4* cRb = (const float4*)(CmL + nRow + lb);
                const float*  zRb = zL + eRow + lb;
                float*        yRb = yL + eRow + lb;

                // Pass 1: local scans from h=0, telescoped decay via sum(d)
                float hA_ = 0.f, hB_ = 0.f, sdA = 0.f, sdB = 0.f;
#pragma unroll 4
                for (int q = 0; q < 32; ++q) {
                    float4 dA = dRa[q], xA = xRa[q], bA = bRa[q];
                    float4 dB = dRb[q], xB = xRb[q], bB = bRb[q];
                    hA_ = __expf(dA.x * A) * hA_ + (dA.x * xA.x) * bA.x;
                    hB_ = __expf(dB.x * A) * hB_ + (dB.x * xB.x) * bB.x;
                    hA_ = __expf(dA.y * A) * hA_ + (dA.y * xA.y) * bA.y;
                    hB_ = __expf(dB.y * A) * hB_ + (dB.y * xB.y) * bB.y;
                    hA_ = __expf(dA.z * A) * hA_ + (dA.z * xA.z) * bA.z;
                    hB_ = __expf(dB.z * A) * hB_ + (dB.z * xB.z) * bB.z;
                    hA_ = __expf(dA.w * A) * hA_ + (dA.w * xA.w) * bA.w;
                    hB_ = __expf(dB.w * A) * hB_ + (dB.w * xB.w) * bB.w;
                    sdA += dA.x + dA.y + dA.z + dA.w;
                    sdB += dB.x + dB.y + dB.z + dB.w;
                }
                sA[2 * gid + 0][n] = __expf(A * sdA);
                sH[2 * gid + 0][n] = hA_;
                sA[2 * gid + 1][n] = __expf(A * sdB);
                sH[2 * gid + 1][n] = hB_;
                __syncthreads();

                // prefix over earlier spans (<=14 LDS folds)
                float h0 = 0.f;
                for (int s = 0; s < 2 * gid; ++s)
                    h0 = sA[s][n] * h0 + sH[s][n];
                hA_ = h0;
                hB_ = sA[2 * gid][n] * h0 + sH[2 * gid][n];

                // Pass 2: rescan with prefixes, reduce over n, gate, store
                int s0 = n & 1, s1 = n & 2;
#pragma unroll 2
                for (int q = 0; q < 32; ++q) {
                    float4 dA = dRa[q], xA = xRa[q], bA = bRa[q], cA = cRa[q];
                    float4 dB = dRb[q], xB = xRb[q], bB = bRb[q], cB = cRb[q];
                    hA_ = __expf(dA.x * A) * hA_ + (dA.x * xA.x) * bA.x;  float pa0 = hA_ * cA.x;
                    hB_ = __expf(dB.x * A) * hB_ + (dB.x * xB.x) * bB.x;  float pb0 = hB_ * cB.x;
                    hA_ = __expf(dA.y * A) * hA_ + (dA.y * xA.y) * bA.y;  float pa1 = hA_ * cA.y;
                    hB_ = __expf(dB.y * A) * hB_ + (dB.y * xB.y) * bB.y;  float pb1 = hB_ * cB.y;
                    hA_ = __expf(dA.z * A) * hA_ + (dA.z * xA.z) * bA.z;  float pa2 = hA_ * cA.z;
                    hB_ = __expf(dB.z * A) * hB_ + (dB.z * xB.z) * bB.z;  float pb2 = hB_ * cB.z;
                    hA_ = __expf(dA.w * A) * hA_ + (dA.w * xA.w) * bA.w;  float pa3 = hA_ * cA.w;
                    hB_ = __expf(dB.w * A) * hB_ + (dB.w * xB.w) * bB.w;  float pb3 = hB_ * cB.w;

                    // butterfly A: lane n%4==k ends with sum over 32 lanes of pa_k
                    float ua  = s0 ? pa1 : pa0;
                    float uas = s0 ? pa0 : pa1;
                    ua += __shfl_xor(uas, 1, 32);
                    float va  = s0 ? pa3 : pa2;
                    float vas = s0 ? pa2 : pa3;
                    va += __shfl_xor(vas, 1, 32);
                    float wa  = s1 ? va : ua;
                    float was = s1 ? ua : va;
                    wa += __shfl_xor(was, 2, 32);
                    wa += __shfl_xor(wa, 4, 32);
                    wa += __shfl_xor(wa, 8, 32);
                    wa += __shfl_xor(wa, 16, 32);
                    // butterfly B
                    float ub  = s0 ? pb1 : pb0;
                    float ubs = s0 ? pb0 : pb1;
                    ub += __shfl_xor(ubs, 1, 32);
                    float vb  = s0 ? pb3 : pb2;
                    float vbs = s0 ? pb2 : pb3;
                    vb += __shfl_xor(vbs, 1, 32);
                    float wb  = s1 ? vb : ub;
                    float wbs = s1 ? ub : vb;
                    wb += __shfl_xor(wbs, 2, 32);
                    wb += __shfl_xor(wb, 4, 32);
                    wb += __shfl_xor(wb, 8, 32);
                    wb += __shfl_xor(wb, 16, 32);

                    if (n < 4) {
                        int l4 = q * 4;
                        float xsa = (n == 0) ? xA.x : (n == 1) ? xA.y
                                  : (n == 2) ? xA.z : xA.w;
                        float yra = wa + Dv * xsa;
                        float zva = zRa[l4 + n];
                        yRa[l4 + n] = yra * (zva / (1.f + __expf(-zva)));
                        float xsb = (n == 0) ? xB.x : (n == 1) ? xB.y
                                  : (n == 2) ? xB.z : xB.w;
                        float yrb = wb + Dv * xsb;
                        float zvb = zRb[l4 + n];
                        yRb[l4 + n] = yrb * (zvb / (1.f + __expf(-zvb)));
                    }
                }
                __syncthreads();   // sA/sH quiescent before next chain
            }
        }
        gbar(layer * 2 + 1);
    }

    // ================= classifier (per group, own batches only) =============
    {
        const float* y3 = ws + (size_t)3 * LSTRIDE + 3 * EDL;
        if (lidx == 0 && tid < NCLASSES) {
            int c = tid;
            for (int bb = b0; bb < bN; ++bb) {
                const float* yp = y3 + (size_t)bb * ED * L_ + (L_ - 1);
                const float* wp = fc_w + c * ED;
                float acc = fc_b[c];
#pragma unroll
                for (int e = 0; e < ED; ++e) acc += yp[(size_t)e * L_] * wp[e];
                out[bb * NCLASSES + c] = acc;
            }
        }
    }
}

// ---------------------------------------------------------------------------
extern "C" void kernel_launch(void* const* d_in, const int* in_sizes, int n_in,
                              void* d_out, int out_size, void* d_ws, size_t ws_size,
                              hipStream_t stream)
{
    const float* x          = (const float*)d_in[0];
    const float* in_proj_w  = (const float*)d_in[1];
    const float* conv_w     = (const float*)d_in[2];
    const float* conv_b     = (const float*)d_in[3];
    const float* x_proj_w   = (const float*)d_in[4];
    const float* dt_proj_w  = (const float*)d_in[5];
    const float* dt_proj_b  = (const float*)d_in[6];
    const float* A_log      = (const float*)d_in[7];
    const float* Dp         = (const float*)d_in[8];
    const float* out_proj_w = (const float*)d_in[9];
    const float* norm_w     = (const float*)d_in[10];
    const float* fc_w       = (const float*)d_in[11];
    const float* fc_b       = (const float*)d_in[12];
    float* ws = (float*)d_ws;

    // zero registration + barrier counters (graph-capturable memset node)
    hipMemsetAsync((void*)(ws + WS_BAR), 0, BAR_BYTES, stream);

    k_all<<<dim3(NBLK), dim3(256), 0, stream>>>(
        x, in_proj_w, conv_w, conv_b, x_proj_w, dt_proj_w, dt_proj_b,
        A_log, Dp, out_proj_w, norm_w, fc_w, fc_b, (float*)d_out, ws);
}

// Round 8
// 386.705 us; speedup vs baseline: 1.4493x; 1.4493x over previous
//
#include <hip/hip_runtime.h>
#include <math.h>

#define B_ 8
#define L_ 2048
#define DM 6
#define ED 48
#define NS 32
#define DCONV 16
#define NLAYERS 4
#define NCLASSES 4
#define EPS 1e-5f

#define NBLK 1024              // 4 blocks/CU co-resident (persistent)
#define TILEW 16
#define NTILE (L_ / TILEW)     // 128 pre-tiles per batch
#define NSPAN 16
#define SPANL (L_ / NSPAN)     // 128 steps per scan span

#define EDL (B_ * ED * L_)     // 786432 floats
#define NSL (B_ * L_ * NS)     // 524288
#define DML (B_ * DM * L_)     // 98304
#define SUMSZ (B_ * ED * NSPAN * NS)   // 196608

// Per-layer buffer instances (write-once per execution -> no stale-L1 hazard,
// no cache maintenance needed in XCD-local mode).
// layout per layer: z, xc, delta, y, Bm, Cm, h, sumA, sumH
#define LSTRIDE (4 * EDL + 2 * NSL + DML + 2 * SUMSZ)
#define WS_BAR (NLAYERS * LSTRIDE)     // float offset of barrier area

#define N_EPOCH 12                     // 3 barriers per layer
// u32 layout at ws+WS_BAR: ureg[8][16] | leaves[9][N_EPOCH][4][16] | masters[9][N_EPOCH][16]
#define UREG_OFF 0
#define LEAF_OFF 128
#define MST_OFF (128 + 9 * N_EPOCH * 4 * 16)
#define BAR_U32 (MST_OFF + 9 * N_EPOCH * 16)
#define BAR_BYTES (BAR_U32 * 4)

// ---------------------------------------------------------------------------
// Round-8: occupancy + depth fix. Round-5/7 counters (VALUBusy 21-24%, HBM
// <3%, Occupancy 23% == the self-imposed 8 waves/CU) show the persistent
// kernel is latency-bound with too little TLP: total scan math is only ~25M
// updates (~4us of VALU) but dependent shfl/L2 chains stall 2-wave SIMDs.
//  * NBLK 1024 + __launch_bounds__(256,4): 16 waves/CU (LDS ~10KB/block).
//  * PRE tiles 16-wide: 128 tiles/batch = 1 per block on its XCD.
//  * SCAN split: P1 = per-(chain,span of 128) local scan -> summaries in
//    L2-local per-layer ws; barrier; P2 = fold <=15 prefixes + rescan +
//    butterfly + gate. Depth 512 -> 256 steps; 1024 groups/XCD all busy.
//  * Bm/Cm back to [b][l][n] (round-6's [b][n][l] float4 reads were
//    uncoalesced: 64 lines/wave-instr -> 10% regression; reverted).
// Fence-free XCD-local barriers as round 5; +4 barriers at ~2-3us each.
// ---------------------------------------------------------------------------

__global__ void __launch_bounds__(256, 4) k_all(
    const float* __restrict__ x,
    const float* __restrict__ in_proj_w,
    const float* __restrict__ conv_w,
    const float* __restrict__ conv_b,
    const float* __restrict__ x_proj_w,
    const float* __restrict__ dt_proj_w,
    const float* __restrict__ dt_proj_b,
    const float* __restrict__ A_log,
    const float* __restrict__ Dp,
    const float* __restrict__ out_proj_w,
    const float* __restrict__ norm_w,
    const float* __restrict__ fc_w,
    const float* __restrict__ fc_b,
    float* __restrict__ out,
    float* __restrict__ ws)
{
    unsigned* bar  = (unsigned*)(ws + WS_BAR);
    unsigned* ureg = bar + UREG_OFF;             // [8][16] per-XCD block counts

    __shared__ float sh[DM][31];     // residual h, 31 positions (l0-15..l0+15)
    __shared__ float sxin[ED][31];   // xin (31 pos); also reused as y-staging
    __shared__ float sxc[ED][17];    // xc, 16 positions (+1 pad)
    __shared__ float srn[31];        // rms scale per position
    __shared__ float sdr[16];        // dt-rank scalar per position
    __shared__ int s_xcd, s_lidx, s_n, s_mode;

    const int tid = threadIdx.x;

    // ---------------- registration: discover block->XCD mapping ------------
    if (tid == 0) {
        unsigned xcd;
        asm volatile("s_getreg_b32 %0, hwreg(HW_REG_XCC_ID)" : "=s"(xcd));
        xcd &= 7u;
        int lidx0 = (int)__hip_atomic_fetch_add(&ureg[xcd * 16], 1u,
                        __ATOMIC_RELAXED, __HIP_MEMORY_SCOPE_AGENT);
        for (;;) {   // poll sum of per-XCD counters (no global atomic chain)
            unsigned tot = 0;
            for (int xx = 0; xx < 8; ++xx)
                tot += __hip_atomic_load(&ureg[xx * 16], __ATOMIC_RELAXED,
                                         __HIP_MEMORY_SCOPE_AGENT);
            if (tot >= (unsigned)NBLK) break;
            __builtin_amdgcn_s_sleep(1);
        }
        int npres = 0;
        for (int xx = 0; xx < 8; ++xx)
            if (__hip_atomic_load(&ureg[xx * 16], __ATOMIC_RELAXED,
                                  __HIP_MEMORY_SCOPE_AGENT)) npres++;
        s_xcd = (int)xcd; s_lidx = lidx0;
        s_n = (int)__hip_atomic_load(&ureg[xcd * 16], __ATOMIC_RELAXED,
                                     __HIP_MEMORY_SCOPE_AGENT);
        s_mode = (npres == 8) ? 0 : 1;
    }
    __syncthreads();

    const int  mode  = s_mode;                 // 0 = XCD-local, 1 = fallback
    const int  grp   = mode ? 8 : s_xcd;       // barrier group id
    const int  lidx  = mode ? (int)blockIdx.x : s_lidx;
    const int  nwork = mode ? NBLK : s_n;
    const int  b0    = mode ? 0 : s_xcd;       // batches this group owns
    const int  bN    = mode ? B_ : s_xcd + 1;

    // two-level group barrier: 4 leaves + master; counters only in mode 0
    auto gbar = [&](int epoch) {
        __syncthreads();
        if (tid == 0) {
            int lf = lidx & 3;
            unsigned quota = (unsigned)((nwork - lf + 3) >> 2);
            unsigned* leaf = bar + LEAF_OFF
                           + (size_t)((grp * N_EPOCH + epoch) * 4 + lf) * 16;
            unsigned* mst  = bar + MST_OFF
                           + (size_t)(grp * N_EPOCH + epoch) * 16;
            if (mode) __threadfence();
            asm volatile("" ::: "memory");
            if (__hip_atomic_fetch_add(leaf, 1u, __ATOMIC_RELAXED,
                                       __HIP_MEMORY_SCOPE_AGENT) == quota - 1)
                __hip_atomic_fetch_add(mst, 1u, __ATOMIC_RELAXED,
                                       __HIP_MEMORY_SCOPE_AGENT);
            while (__hip_atomic_load(mst, __ATOMIC_RELAXED,
                                     __HIP_MEMORY_SCOPE_AGENT) < 4u)
                __builtin_amdgcn_s_sleep(2);
            asm volatile("" ::: "memory");
            if (mode) __threadfence();
        }
        __syncthreads();
    };

    for (int layer = 0; layer < NLAYERS; ++layer) {
        const float* ipw = in_proj_w + (size_t)layer * 96 * DM;
        const float* nw  = norm_w    + (size_t)layer * DM;
        const float* cw  = conv_w    + (size_t)layer * ED * DCONV;
        const float* cb  = conv_b    + (size_t)layer * ED;
        const float* xpw = x_proj_w  + (size_t)layer * 65 * ED;
        const float* dtw = dt_proj_w + (size_t)layer * ED;
        const float* dtb = dt_proj_b + (size_t)layer * ED;
        const float* al  = A_log     + (size_t)layer * ED * NS;
        const float* dpp = Dp        + (size_t)layer * ED;
        const float* ow  = (layer == 0) ? out_proj_w
                          : out_proj_w + (size_t)(layer - 1) * DM * ED;

        float* Lb    = ws + (size_t)layer * LSTRIDE;
        float* zL    = Lb;
        float* xcL   = zL  + EDL;
        float* dL    = xcL + EDL;
        float* yL    = dL  + EDL;
        float* BmL   = yL  + EDL;                    // [b][l][n]
        float* CmL   = BmL + NSL;                    // [b][l][n]
        float* hL    = CmL + NSL;
        float* saL   = hL  + DML;                    // span summaries exp(A*sum d)
        float* shL   = saL + SUMSZ;                  // span summaries local end h
        const float* hprev = (layer > 0) ? (ws + (size_t)(layer-1) * LSTRIDE
                                            + 4 * EDL + 2 * NSL) : nullptr;
        const float* yprev = (layer > 0) ? (ws + (size_t)(layer-1) * LSTRIDE
                                            + 3 * EDL) : nullptr;

        // ================= PRE: 128 16-wide tiles per batch =================
        for (int bb = b0; bb < bN; ++bb) {
            for (int t = lidx; t < NTILE; t += nwork) {
                const int b  = bb;
                const int l0 = t * TILEW;

                // Phase 1: residual h for 31 positions (15 halo + 16 owned)
                if (layer > 0) {
                    for (int i = tid; i < ED * 31; i += 256) {
                        int e = i / 31, p = i % 31;
                        int l = l0 - 15 + p;
                        sxin[e][p] = (l >= 0)
                            ? yprev[((size_t)b * ED + e) * L_ + l] : 0.f;
                    }
                    __syncthreads();
                    for (int i = tid; i < DM * 31; i += 256) {
                        int d = i / 31, p = i % 31;
                        int l = l0 - 15 + p;
                        float hv = 0.f;
                        if (l >= 0) {
                            hv = hprev[((size_t)b * DM + d) * L_ + l];
                            const float* wp = ow + d * ED;
                            float acc = 0.f;
#pragma unroll
                            for (int e = 0; e < ED; ++e) acc += sxin[e][p] * wp[e];
                            hv += acc;
                            if (p >= 15 && layer < NLAYERS - 1)
                                hL[((size_t)b * DM + d) * L_ + l] = hv;
                        }
                        sh[d][p] = hv;
                    }
                } else {
                    for (int i = tid; i < DM * 31; i += 256) {
                        int d = i / 31, p = i % 31;
                        int l = l0 - 15 + p;
                        float hv = 0.f;
                        if (l >= 0) {
                            hv = x[((size_t)b * L_ + l) * DM + d];
                            if (p >= 15)
                                hL[((size_t)b * DM + d) * L_ + l] = hv;
                        }
                        sh[d][p] = hv;
                    }
                }
                __syncthreads();

                // Phase 2: rms scale per position
                if (tid < 31) {
                    float ss = 0.f;
#pragma unroll
                    for (int d = 0; d < DM; ++d) ss += sh[d][tid] * sh[d][tid];
                    srn[tid] = rsqrtf(ss * (1.f / DM) + EPS);
                }
                __syncthreads();

                // Phase 3a: xin (31 positions, into LDS)
                for (int i = tid; i < ED * 31; i += 256) {
                    int e = i / 31, p = i % 31;
                    const float* wp = ipw + e * DM;
                    float acc = 0.f;
#pragma unroll
                    for (int d = 0; d < DM; ++d) acc += sh[d][p] * nw[d] * wp[d];
                    sxin[e][p] = acc * srn[p];
                }
                // Phase 3b: z (16 owned positions, to global)
                for (int i = tid; i < ED * TILEW; i += 256) {
                    int e = i >> 4, po = i & 15;
                    int p = po + 15;
                    const float* wp = ipw + (ED + e) * DM;
                    float acc = 0.f;
#pragma unroll
                    for (int d = 0; d < DM; ++d) acc += sh[d][p] * nw[d] * wp[d];
                    zL[((size_t)b * ED + e) * L_ + l0 + po] = acc * srn[p];
                }
                __syncthreads();

                // Phase 4: conv + SiLU
                for (int i = tid; i < ED * TILEW; i += 256) {
                    int e = i >> 4, po = i & 15;
                    const float* wp = cw + e * DCONV;
                    float acc = cb[e];
#pragma unroll
                    for (int k = 0; k < DCONV; ++k) acc += sxin[e][po + k] * wp[k];
                    float v = acc / (1.f + __expf(-acc));
                    sxc[e][po] = v;
                    xcL[((size_t)b * ED + e) * L_ + l0 + po] = v;
                }
                __syncthreads();

                // Phase 5: x_proj. 16 output-groups of 4 rows; li = position.
                {
                    int og = tid >> 4, li = tid & 15;
                    int isB = og < 8;
                    int nb = (og & 7) * 4;
                    int rowBase = isB ? (1 + nb) : (1 + NS + nb);
                    const float* wr = xpw + rowBase * ED;
                    float a0=0,a1=0,a2=0,a3=0, dr=0;
#pragma unroll 4
                    for (int e = 0; e < ED; ++e) {
                        float xv = sxc[e][li];
                        a0 += xv * wr[0*ED+e]; a1 += xv * wr[1*ED+e];
                        a2 += xv * wr[2*ED+e]; a3 += xv * wr[3*ED+e];
                        dr += xv * xpw[e];
                    }
                    float* outp = (isB ? BmL : CmL)
                                + ((size_t)(b * L_ + l0 + li)) * NS + nb;
                    *(float4*)outp = make_float4(a0, a1, a2, a3);
                    if (og == 0) sdr[li] = dr;
                }
                __syncthreads();

                // Phase 6: delta = softplus(dr*dtw + dtb)
                for (int i = tid; i < ED * TILEW; i += 256) {
                    int e = i >> 4, po = i & 15;
                    float s = sdr[po] * dtw[e] + dtb[e];
                    dL[((size_t)b * ED + e) * L_ + l0 + po] =
                        fmaxf(s, 0.f) + log1pf(__expf(-fabsf(s)));
                }
                __syncthreads();   // LDS quiescent before next tile
            }
        }
        gbar(layer * 3 + 0);

        // ================= SCAN P1: per-(chain,span) local scan =============
        // task g -> (b, e, span s of 128 steps); 32-lane group per task.
        {
            const int gid = tid >> 5;
            const int n   = tid & 31;
            const int T   = (bN - b0) * ED * NSPAN;
            for (int g = lidx * 8 + gid; g < T; g += nwork * 8) {
                int bb = b0 + g / (ED * NSPAN);
                int r  = g % (ED * NSPAN);
                int e  = r >> 4;
                int s  = r & 15;
                float A = -__expf(al[e * NS + n]);
                size_t eRow = (size_t)(bb * ED + e) * L_ + s * SPANL;
                const float4* dRow = (const float4*)(dL + eRow);
                const float4* xRow = (const float4*)(xcL + eRow);
                const float* bBase = BmL + ((size_t)bb * L_ + s * SPANL) * NS + n;
                float h = 0.f, sd = 0.f;
#pragma unroll 4
                for (int q = 0; q < SPANL / 4; ++q) {
                    float4 d4 = dRow[q];
                    float4 x4 = xRow[q];
                    float v0 = bBase[(4 * q + 0) * NS];
                    float v1 = bBase[(4 * q + 1) * NS];
                    float v2 = bBase[(4 * q + 2) * NS];
                    float v3 = bBase[(4 * q + 3) * NS];
                    h = __expf(d4.x * A) * h + (d4.x * x4.x) * v0;
                    h = __expf(d4.y * A) * h + (d4.y * x4.y) * v1;
                    h = __expf(d4.z * A) * h + (d4.z * x4.z) * v2;
                    h = __expf(d4.w * A) * h + (d4.w * x4.w) * v3;
                    sd += d4.x + d4.y + d4.z + d4.w;
                }
                size_t idx = ((size_t)(bb * ED + e) * NSPAN + s) * NS + n;
                saL[idx] = __expf(A * sd);
                shL[idx] = h;
            }
        }
        gbar(layer * 3 + 1);

        // ================= SCAN P2: prefix fold + rescan + gate =============
        {
            const int gid = tid >> 5;
            const int n   = tid & 31;
            const int T   = (bN - b0) * ED * NSPAN;
            for (int g = lidx * 8 + gid; g < T; g += nwork * 8) {
                int bb = b0 + g / (ED * NSPAN);
                int r  = g % (ED * NSPAN);
                int e  = r >> 4;
                int s  = r & 15;
                float A  = -__expf(al[e * NS + n]);
                float Dv = dpp[e];

                // exclusive prefix over this chain's earlier span summaries
                float h = 0.f;
                size_t sbase = (size_t)(bb * ED + e) * NSPAN * NS + n;
                for (int sp = 0; sp < s; ++sp)
                    h = saL[sbase + sp * NS] * h + shL[sbase + sp * NS];

                size_t eRow = (size_t)(bb * ED + e) * L_ + s * SPANL;
                size_t nRow = ((size_t)bb * L_ + s * SPANL) * NS + n;
                const float4* dRow = (const float4*)(dL + eRow);
                const float4* xRow = (const float4*)(xcL + eRow);
                const float* bBase = BmL + nRow;
                const float* cBase = CmL + nRow;
                const float* zRow  = zL + eRow;
                float*       yRow  = yL + eRow;
                int s0 = n & 1, s1 = n & 2;
#pragma unroll 2
                for (int q = 0; q < SPANL / 4; ++q) {
                    float4 d4 = dRow[q];
                    float4 x4 = xRow[q];
                    float bb0 = bBase[(4 * q + 0) * NS];
                    float bb1 = bBase[(4 * q + 1) * NS];
                    float bb2 = bBase[(4 * q + 2) * NS];
                    float bb3 = bBase[(4 * q + 3) * NS];
                    float cc0 = cBase[(4 * q + 0) * NS];
                    float cc1 = cBase[(4 * q + 1) * NS];
                    float cc2 = cBase[(4 * q + 2) * NS];
                    float cc3 = cBase[(4 * q + 3) * NS];
                    h = __expf(d4.x * A) * h + (d4.x * x4.x) * bb0;  float p0 = h * cc0;
                    h = __expf(d4.y * A) * h + (d4.y * x4.y) * bb1;  float p1 = h * cc1;
                    h = __expf(d4.z * A) * h + (d4.z * x4.z) * bb2;  float p2 = h * cc2;
                    h = __expf(d4.w * A) * h + (d4.w * x4.w) * bb3;  float p3 = h * cc3;
                    // multi-value butterfly: lane n%4==k sums p_k over 32 lanes
                    float u  = s0 ? p1 : p0;
                    float us = s0 ? p0 : p1;
                    u += __shfl_xor(us, 1, 32);
                    float v  = s0 ? p3 : p2;
                    float vs = s0 ? p2 : p3;
                    v += __shfl_xor(vs, 1, 32);
                    float wv  = s1 ? v : u;
                    float wvs = s1 ? u : v;
                    wv += __shfl_xor(wvs, 2, 32);
                    wv += __shfl_xor(wv, 4, 32);
                    wv += __shfl_xor(wv, 8, 32);
                    wv += __shfl_xor(wv, 16, 32);
                    if (n < 4) {
                        int l4 = q * 4;
                        float xs = (n == 0) ? x4.x : (n == 1) ? x4.y
                                 : (n == 2) ? x4.z : x4.w;
                        float yr = wv + Dv * xs;
                        float zv = zRow[l4 + n];
                        yRow[l4 + n] = yr * (zv / (1.f + __expf(-zv)));
                    }
                }
            }
        }
        gbar(layer * 3 + 2);
    }

    // ================= classifier (per group, own batches only) =============
    {
        const float* y3 = ws + (size_t)3 * LSTRIDE + 3 * EDL;
        if (lidx == 0 && tid < NCLASSES) {
            int c = tid;
            for (int bb = b0; bb < bN; ++bb) {
                const float* yp = y3 + (size_t)bb * ED * L_ + (L_ - 1);
                const float* wp = fc_w + c * ED;
                float acc = fc_b[c];
#pragma unroll
                for (int e = 0; e < ED; ++e) acc += yp[(size_t)e * L_] * wp[e];
                out[bb * NCLASSES + c] = acc;
            }
        }
    }
}

// ---------------------------------------------------------------------------
extern "C" void kernel_launch(void* const* d_in, const int* in_sizes, int n_in,
                              void* d_out, int out_size, void* d_ws, size_t ws_size,
                              hipStream_t stream)
{
    const float* x          = (const float*)d_in[0];
    const float* in_proj_w  = (const float*)d_in[1];
    const float* conv_w     = (const float*)d_in[2];
    const float* conv_b     = (const float*)d_in[3];
    const float* x_proj_w   = (const float*)d_in[4];
    const float* dt_proj_w  = (const float*)d_in[5];
    const float* dt_proj_b  = (const float*)d_in[6];
    const float* A_log      = (const float*)d_in[7];
    const float* Dp         = (const float*)d_in[8];
    const float* out_proj_w = (const float*)d_in[9];
    const float* norm_w     = (const float*)d_in[10];
    const float* fc_w       = (const float*)d_in[11];
    const float* fc_b       = (const float*)d_in[12];
    float* ws = (float*)d_ws;

    // zero registration + barrier counters (graph-capturable memset node)
    hipMemsetAsync((void*)(ws + WS_BAR), 0, BAR_BYTES, stream);

    k_all<<<dim3(NBLK), dim3(256), 0, stream>>>(
        x, in_proj_w, conv_w, conv_b, x_proj_w, dt_proj_w, dt_proj_b,
        A_log, Dp, out_proj_w, norm_w, fc_w, fc_b, (float*)d_out, ws);
}